// Round 1
// baseline (383.312 us; speedup 1.0000x reference)
//
#include <hip/hip_runtime.h>
#include <hip/hip_fp16.h>

// WordAttention on MI355X: fp16 MFMA pipeline.
//   q,k,v = x@W + b  (fp16 out);  S = q k^T (fp32);  P = softmax(S) (fp16);  out = P v (fp32)
// All GEMMs are C[M][N] = A[M][K] * Bt[N][K]^T with K contiguous in both operands.

typedef _Float16 f16;
typedef __attribute__((ext_vector_type(8))) _Float16 f16x8;
typedef __attribute__((ext_vector_type(4))) _Float16 f16x4;
typedef __attribute__((ext_vector_type(4))) float f32x4;

#define GADDR(p) ((const __attribute__((address_space(1))) void*)(p))
#define LADDR(p) ((__attribute__((address_space(3))) void*)(p))

// ---------------- convert x: fp32 -> fp16, 4 elems/thread ----------------
__global__ __launch_bounds__(256) void k_cvt_x(const float* __restrict__ in,
                                               f16* __restrict__ out) {
    long i = (long)blockIdx.x * 256 + threadIdx.x;   // over n/4
    float4 v = ((const float4*)in)[i];
    f16x4 h = { (f16)v.x, (f16)v.y, (f16)v.z, (f16)v.w };
    ((f16x4*)out)[i] = h;
}

// ------------- convert+transpose weights: Wt[w][n][k] = W[w][k][n] -------------
__global__ __launch_bounds__(256) void k_cvt_w(const float* __restrict__ Wq,
                                               const float* __restrict__ Wk,
                                               const float* __restrict__ Wv,
                                               f16* __restrict__ Wt) {
    int id = blockIdx.x * 256 + threadIdx.x;         // 3*512*512 total
    int w = id >> 18, rem = id & 262143;
    int kk = rem >> 9, n = rem & 511;
    const float* W = (w == 0) ? Wq : (w == 1) ? Wk : Wv;
    Wt[((long)w << 18) + ((long)n << 9) + kk] = (f16)W[((long)kk << 9) + n];
}

// ------------- per-batch transpose: Vt[b][d][s] = V[b*2048+s][d] -------------
__global__ __launch_bounds__(256) void k_transpose_v(const f16* __restrict__ V,
                                                     f16* __restrict__ Vt) {
    __shared__ f16 t[32][33];                        // +1 pad vs bank conflicts
    int b = blockIdx.z, s0 = blockIdx.y * 32, d0 = blockIdx.x * 32;
    int x = threadIdx.x & 31, y = threadIdx.x >> 5;  // 32 x 8
#pragma unroll
    for (int i = 0; i < 4; ++i)
        t[y + i * 8][x] = V[((long)(b * 2048 + s0 + y + i * 8) << 9) + d0 + x];
    __syncthreads();
#pragma unroll
    for (int i = 0; i < 4; ++i)
        Vt[((long)(b * 512 + d0 + y + i * 8) << 11) + s0 + x] = t[x][y + i * 8];
}

// ---------------- GEMM: C = A[M][K] * Bt[N][K]^T (+bias), m97 structure ----------------
// 128x128 tile, BK=32, 4 waves each computing 64x64 (4x4 frags of 16x16x32 f16 MFMA).
template <bool OUT_F16, bool BIAS>
__global__ __launch_bounds__(256) void k_gemm(const f16* __restrict__ A,
                                              const f16* __restrict__ Bt,
                                              void* __restrict__ Cv,
                                              const float* __restrict__ bias,
                                              int M, int N, int K,
                                              long sA, long sB, long sC) {
    const int bz = blockIdx.z;
    A  += bz * sA;
    Bt += bz * sB;
    __shared__ f16 As[128][32];
    __shared__ f16 Bs[128][32];
    const int tid = threadIdx.x;
    const int wave = tid >> 6, lane = tid & 63;
    const int l15 = lane & 15, l4 = lane >> 4;       // frag row/col, k-chunk
    const int wm = (wave >> 1) * 64, wn = (wave & 1) * 64;
    const long rowA0 = (long)blockIdx.y * 128;
    const long rowB0 = (long)blockIdx.x * 128;

    // staging: chunk c = i*256 + tid maps to LDS byte c*16 = row*64 + kc*16
    const int trow = tid >> 2;                       // 0..63
    const int tkc  = (tid & 3) * 8;                  // k elem offset
    f16* AsF = &As[0][0];
    f16* BsF = &Bs[0][0];

    f32x4 acc[4][4] = {};

    for (int k0 = 0; k0 < K; k0 += 32) {
        __syncthreads();                             // WAR: prev tile reads done
        {
            const f16* ga0 = A  + (rowA0 + trow)      * (long)K + k0 + tkc;
            const f16* ga1 = A  + (rowA0 + trow + 64) * (long)K + k0 + tkc;
            const f16* gb0 = Bt + (rowB0 + trow)      * (long)K + k0 + tkc;
            const f16* gb1 = Bt + (rowB0 + trow + 64) * (long)K + k0 + tkc;
            __builtin_amdgcn_global_load_lds(GADDR(ga0), LADDR((char*)AsF + wave * 1024), 16, 0, 0);
            __builtin_amdgcn_global_load_lds(GADDR(ga1), LADDR((char*)AsF + 4096 + wave * 1024), 16, 0, 0);
            __builtin_amdgcn_global_load_lds(GADDR(gb0), LADDR((char*)BsF + wave * 1024), 16, 0, 0);
            __builtin_amdgcn_global_load_lds(GADDR(gb1), LADDR((char*)BsF + 4096 + wave * 1024), 16, 0, 0);
        }
        __syncthreads();                             // staging complete (vmcnt drained)

        f16x8 af[4], bf[4];
#pragma unroll
        for (int i = 0; i < 4; ++i)
            af[i] = *(const f16x8*)&As[wm + i * 16 + l15][l4 * 8];
#pragma unroll
        for (int i = 0; i < 4; ++i)
            bf[i] = *(const f16x8*)&Bs[wn + i * 16 + l15][l4 * 8];
#pragma unroll
        for (int i = 0; i < 4; ++i)
#pragma unroll
            for (int j = 0; j < 4; ++j)
                acc[i][j] = __builtin_amdgcn_mfma_f32_16x16x32_f16(af[i], bf[j], acc[i][j], 0, 0, 0);
    }

    // epilogue: C/D layout col = lane&15, row = (lane>>4)*4 + reg  [m89-verified]
    if constexpr (OUT_F16) {
        f16* C = (f16*)Cv + bz * sC;
#pragma unroll
        for (int i = 0; i < 4; ++i)
#pragma unroll
            for (int j = 0; j < 4; ++j) {
                long gr = rowA0 + wm + i * 16 + l4 * 4;
                int  gc = (int)rowB0 + wn + j * 16 + l15;
                float bv_ = BIAS ? bias[gc] : 0.f;
#pragma unroll
                for (int r = 0; r < 4; ++r)
                    C[(gr + r) * (long)N + gc] = (f16)(acc[i][j][r] + bv_);
            }
    } else {
        float* C = (float*)Cv + bz * sC;
#pragma unroll
        for (int i = 0; i < 4; ++i)
#pragma unroll
            for (int j = 0; j < 4; ++j) {
                long gr = rowA0 + wm + i * 16 + l4 * 4;
                int  gc = (int)rowB0 + wn + j * 16 + l15;
                float bv_ = BIAS ? bias[gc] : 0.f;
#pragma unroll
                for (int r = 0; r < 4; ++r)
                    C[(gr + r) * (long)N + gc] = acc[i][j][r] + bv_;
            }
    }
}

// ---------------- row softmax: S fp32 [2048 cols] -> P fp16 ----------------
__global__ __launch_bounds__(256) void k_softmax(const float* __restrict__ S,
                                                 f16* __restrict__ P) {
    const int row = blockIdx.x;
    const float* s = S + (long)row * 2048;
    const int tid = threadIdx.x, lane = tid & 63, wave = tid >> 6;

    float4 v0 = ((const float4*)s)[tid * 2];
    float4 v1 = ((const float4*)s)[tid * 2 + 1];
    float m = fmaxf(fmaxf(fmaxf(v0.x, v0.y), fmaxf(v0.z, v0.w)),
                    fmaxf(fmaxf(v1.x, v1.y), fmaxf(v1.z, v1.w)));
#pragma unroll
    for (int off = 32; off; off >>= 1) m = fmaxf(m, __shfl_xor(m, off));

    __shared__ float red[4];
    __shared__ float bc[2];
    if (lane == 0) red[wave] = m;
    __syncthreads();
    if (tid == 0) bc[0] = fmaxf(fmaxf(red[0], red[1]), fmaxf(red[2], red[3]));
    __syncthreads();
    m = bc[0];

    float e[8];
    e[0] = __expf(v0.x - m); e[1] = __expf(v0.y - m);
    e[2] = __expf(v0.z - m); e[3] = __expf(v0.w - m);
    e[4] = __expf(v1.x - m); e[5] = __expf(v1.y - m);
    e[6] = __expf(v1.z - m); e[7] = __expf(v1.w - m);
    float sum = ((e[0] + e[1]) + (e[2] + e[3])) + ((e[4] + e[5]) + (e[6] + e[7]));
#pragma unroll
    for (int off = 32; off; off >>= 1) sum += __shfl_xor(sum, off);
    if (lane == 0) red[wave] = sum;
    __syncthreads();
    if (tid == 0) bc[1] = (red[0] + red[1]) + (red[2] + red[3]);
    __syncthreads();
    float inv = 1.f / bc[1];

    f16x8 o;
#pragma unroll
    for (int j = 0; j < 8; ++j) o[j] = (f16)(e[j] * inv);
    ((f16x8*)(P + (long)row * 2048))[tid] = o;
}

extern "C" void kernel_launch(void* const* d_in, const int* in_sizes, int n_in,
                              void* d_out, int out_size, void* d_ws, size_t ws_size,
                              hipStream_t stream) {
    const float* x  = (const float*)d_in[0];
    const float* Wq = (const float*)d_in[1];
    const float* bq = (const float*)d_in[2];
    const float* Wk = (const float*)d_in[3];
    const float* bk = (const float*)d_in[4];
    const float* Wv = (const float*)d_in[5];
    const float* bv = (const float*)d_in[6];
    float* out = (float*)d_out;

    // ---- workspace layout (98 MiB total) ----
    char* ws = (char*)d_ws;
    f16*   qh = (f16*)(ws + 0);                       // [16384][512] fp16
    f16*   kh = (f16*)(ws + 16777216);                // [16384][512]
    f16*   vt = (f16*)(ws + 33554432);                // [8][512][2048]
    f16*   Wt = (f16*)(ws + 50331648);                // [3][512][512]
    float* sc = (float*)(ws + 52428800);              // [2048][2048] fp32 (1 batch, reused)
    f16*   P4 = (f16*)(ws + 69206016);                // [4][2048][2048] fp16 (group of 4 batches)
    // d_out doubles as scratch before the final PV overwrites it:
    f16* xh = (f16*)d_out;                            // [16384][512] fp16
    f16* vv = (f16*)((char*)d_out + 16777216);        // [16384][512] fp16

    k_cvt_x<<<8192, 256, 0, stream>>>(x, xh);
    k_cvt_w<<<3072, 256, 0, stream>>>(Wq, Wk, Wv, Wt);

    // QKV projections: M=16384, N=512, K=512
    dim3 gProj(4, 128, 1);
    k_gemm<true, true><<<gProj, 256, 0, stream>>>(xh, Wt,          qh, bq, 16384, 512, 512, 0, 0, 0);
    k_gemm<true, true><<<gProj, 256, 0, stream>>>(xh, Wt + 262144, kh, bk, 16384, 512, 512, 0, 0, 0);
    k_gemm<true, true><<<gProj, 256, 0, stream>>>(xh, Wt + 524288, vv, bv, 16384, 512, 512, 0, 0, 0);

    k_transpose_v<<<dim3(16, 64, 8), 256, 0, stream>>>(vv, vt);

    // attention, in 2 groups of 4 batches so the PV launch fills all 256 CUs
    for (int g = 0; g < 2; ++g) {
        for (int b = 0; b < 4; ++b) {
            long bb = g * 4 + b;
            k_gemm<false, false><<<dim3(16, 16, 1), 256, 0, stream>>>(
                qh + bb * 2048 * 512, kh + bb * 2048 * 512, sc, nullptr,
                2048, 2048, 512, 0, 0, 0);
            k_softmax<<<2048, 256, 0, stream>>>(sc, P4 + (long)b * 2048 * 2048);
        }
        k_gemm<false, false><<<dim3(4, 16, 4), 256, 0, stream>>>(
            P4, vt + (long)g * 4 * 512 * 2048, out + (long)g * 4 * 2048 * 512, nullptr,
            2048, 512, 2048,
            (long)2048 * 2048, (long)512 * 2048, (long)2048 * 512);
    }
}

// Round 2
// 212.715 us; speedup vs baseline: 1.8020x; 1.8020x over previous
//
#include <hip/hip_runtime.h>
#include <hip/hip_fp16.h>

// WordAttention on MI355X: fp16 MFMA pipeline, fully batched launches.
//   q,k,v = x@W + b (fp16);  S = q k^T (fp16, z=8);  P = softmax(S) in-place;  out = P v (fp32, z=8)

typedef _Float16 f16;
typedef __attribute__((ext_vector_type(8))) _Float16 f16x8;
typedef __attribute__((ext_vector_type(4))) _Float16 f16x4;
typedef __attribute__((ext_vector_type(4))) float f32x4;

#define GADDR(p) ((const __attribute__((address_space(1))) void*)(p))
#define LADDR(p) ((__attribute__((address_space(3))) void*)(p))

// ---------------- convert x: fp32 -> fp16, 4 elems/thread ----------------
__global__ __launch_bounds__(256) void k_cvt_x(const float* __restrict__ in,
                                               f16* __restrict__ out) {
    long i = (long)blockIdx.x * 256 + threadIdx.x;
    float4 v = ((const float4*)in)[i];
    f16x4 h = { (f16)v.x, (f16)v.y, (f16)v.z, (f16)v.w };
    ((f16x4*)out)[i] = h;
}

// ------------- convert+transpose weights: Wt[w][n][k] = W[w][k][n] -------------
__global__ __launch_bounds__(256) void k_cvt_w(const float* __restrict__ Wq,
                                               const float* __restrict__ Wk,
                                               const float* __restrict__ Wv,
                                               f16* __restrict__ Wt) {
    int id = blockIdx.x * 256 + threadIdx.x;
    int w = id >> 18, rem = id & 262143;
    int kk = rem >> 9, n = rem & 511;
    const float* W = (w == 0) ? Wq : (w == 1) ? Wk : Wv;
    Wt[((long)w << 18) + ((long)n << 9) + kk] = (f16)W[((long)kk << 9) + n];
}

// ------------- per-batch transpose: Vt[b][d][s] = V[b*2048+s][d] -------------
__global__ __launch_bounds__(256) void k_transpose_v(const f16* __restrict__ V,
                                                     f16* __restrict__ Vt) {
    __shared__ f16 t[32][33];
    int b = blockIdx.z, s0 = blockIdx.y * 32, d0 = blockIdx.x * 32;
    int x = threadIdx.x & 31, y = threadIdx.x >> 5;
#pragma unroll
    for (int i = 0; i < 4; ++i)
        t[y + i * 8][x] = V[((long)(b * 2048 + s0 + y + i * 8) << 9) + d0 + x];
    __syncthreads();
#pragma unroll
    for (int i = 0; i < 4; ++i)
        Vt[((long)(b * 512 + d0 + y + i * 8) << 11) + s0 + x] = t[x][y + i * 8];
}

// ---------------- GEMM: C = A[M][K] * Bt[N][K]^T, m97 structure ----------------
// 128x128 tile, BK=32, 4 waves each computing 64x64 (4x4 frags of 16x16x32 f16 MFMA).
// QKV mode: Bt indexed by z (3 weight mats), C -> qh/kh (z<2, contiguous) or CvAlt (z=2), +bias.
template <bool OUT_F16, bool QKV>
__global__ __launch_bounds__(256) void k_gemm(const f16* __restrict__ A,
                                              const f16* __restrict__ Bt,
                                              void* __restrict__ Cv,
                                              void* __restrict__ CvAlt,
                                              const float* __restrict__ b0,
                                              const float* __restrict__ b1,
                                              const float* __restrict__ b2,
                                              int M, int N, int K,
                                              long sA, long sB, long sC) {
    const int bz = blockIdx.z;
    A  += bz * sA;
    Bt += bz * sB;
    __shared__ f16 As[128][32];
    __shared__ f16 Bs[128][32];
    const int tid = threadIdx.x;
    const int wave = tid >> 6, lane = tid & 63;
    const int l15 = lane & 15, l4 = lane >> 4;
    const int wm = (wave >> 1) * 64, wn = (wave & 1) * 64;
    const long rowA0 = (long)blockIdx.y * 128;
    const long rowB0 = (long)blockIdx.x * 128;

    const int trow = tid >> 2;
    const int tkc  = (tid & 3) * 8;
    f16* AsF = &As[0][0];
    f16* BsF = &Bs[0][0];

    f32x4 acc[4][4] = {};

    for (int k0 = 0; k0 < K; k0 += 32) {
        __syncthreads();
        {
            const f16* ga0 = A  + (rowA0 + trow)      * (long)K + k0 + tkc;
            const f16* ga1 = A  + (rowA0 + trow + 64) * (long)K + k0 + tkc;
            const f16* gb0 = Bt + (rowB0 + trow)      * (long)K + k0 + tkc;
            const f16* gb1 = Bt + (rowB0 + trow + 64) * (long)K + k0 + tkc;
            __builtin_amdgcn_global_load_lds(GADDR(ga0), LADDR((char*)AsF + wave * 1024), 16, 0, 0);
            __builtin_amdgcn_global_load_lds(GADDR(ga1), LADDR((char*)AsF + 4096 + wave * 1024), 16, 0, 0);
            __builtin_amdgcn_global_load_lds(GADDR(gb0), LADDR((char*)BsF + wave * 1024), 16, 0, 0);
            __builtin_amdgcn_global_load_lds(GADDR(gb1), LADDR((char*)BsF + 4096 + wave * 1024), 16, 0, 0);
        }
        __syncthreads();

        f16x8 af[4], bf[4];
#pragma unroll
        for (int i = 0; i < 4; ++i)
            af[i] = *(const f16x8*)&As[wm + i * 16 + l15][l4 * 8];
#pragma unroll
        for (int i = 0; i < 4; ++i)
            bf[i] = *(const f16x8*)&Bs[wn + i * 16 + l15][l4 * 8];
#pragma unroll
        for (int i = 0; i < 4; ++i)
#pragma unroll
            for (int j = 0; j < 4; ++j)
                acc[i][j] = __builtin_amdgcn_mfma_f32_16x16x32_f16(af[i], bf[j], acc[i][j], 0, 0, 0);
    }

    // epilogue: C/D layout col = lane&15, row = (lane>>4)*4 + reg  [m89-verified]
    const float* bias = nullptr;
    if constexpr (QKV) bias = (bz == 0) ? b0 : (bz == 1) ? b1 : b2;

    if constexpr (OUT_F16) {
        f16* C;
        if constexpr (QKV) C = (bz < 2) ? (f16*)Cv + bz * sC : (f16*)CvAlt;
        else               C = (f16*)Cv + bz * sC;
#pragma unroll
        for (int i = 0; i < 4; ++i)
#pragma unroll
            for (int j = 0; j < 4; ++j) {
                long gr = rowA0 + wm + i * 16 + l4 * 4;
                int  gc = (int)rowB0 + wn + j * 16 + l15;
                float bv_ = QKV ? bias[gc] : 0.f;
#pragma unroll
                for (int r = 0; r < 4; ++r)
                    C[(gr + r) * (long)N + gc] = (f16)(acc[i][j][r] + bv_);
            }
    } else {
        float* C = (float*)Cv + bz * sC;
#pragma unroll
        for (int i = 0; i < 4; ++i)
#pragma unroll
            for (int j = 0; j < 4; ++j) {
                long gr = rowA0 + wm + i * 16 + l4 * 4;
                int  gc = (int)rowB0 + wn + j * 16 + l15;
#pragma unroll
                for (int r = 0; r < 4; ++r)
                    C[(gr + r) * (long)N + gc] = acc[i][j][r];
            }
    }
}

// ---------------- row softmax in place: fp16 [2048 cols] ----------------
__global__ __launch_bounds__(256) void k_softmax(f16* __restrict__ P) {
    const long row = blockIdx.x;
    f16* p = P + row * 2048;
    const int tid = threadIdx.x, lane = tid & 63, wave = tid >> 6;

    f16x8 v = ((const f16x8*)p)[tid];
    float f[8];
#pragma unroll
    for (int j = 0; j < 8; ++j) f[j] = (float)v[j];
    float m = fmaxf(fmaxf(fmaxf(f[0], f[1]), fmaxf(f[2], f[3])),
                    fmaxf(fmaxf(f[4], f[5]), fmaxf(f[6], f[7])));
#pragma unroll
    for (int off = 32; off; off >>= 1) m = fmaxf(m, __shfl_xor(m, off));

    __shared__ float red[4];
    __shared__ float bc[2];
    if (lane == 0) red[wave] = m;
    __syncthreads();
    if (tid == 0) bc[0] = fmaxf(fmaxf(red[0], red[1]), fmaxf(red[2], red[3]));
    __syncthreads();
    m = bc[0];

    float e[8], sum = 0.f;
#pragma unroll
    for (int j = 0; j < 8; ++j) { e[j] = __expf(f[j] - m); sum += e[j]; }
#pragma unroll
    for (int off = 32; off; off >>= 1) sum += __shfl_xor(sum, off);
    if (lane == 0) red[wave] = sum;
    __syncthreads();
    if (tid == 0) bc[1] = (red[0] + red[1]) + (red[2] + red[3]);
    __syncthreads();
    float inv = 1.f / bc[1];

    f16x8 o;
#pragma unroll
    for (int j = 0; j < 8; ++j) o[j] = (f16)(e[j] * inv);
    ((f16x8*)p)[tid] = o;
}

extern "C" void kernel_launch(void* const* d_in, const int* in_sizes, int n_in,
                              void* d_out, int out_size, void* d_ws, size_t ws_size,
                              hipStream_t stream) {
    const float* x  = (const float*)d_in[0];
    const float* Wq = (const float*)d_in[1];
    const float* bq = (const float*)d_in[2];
    const float* Wk = (const float*)d_in[3];
    const float* bk = (const float*)d_in[4];
    const float* Wv = (const float*)d_in[5];
    const float* bv = (const float*)d_in[6];
    float* out = (float*)d_out;

    // ---- workspace layout (96 MiB peak, phase-aliased) ----
    char* ws = (char*)d_ws;
    f16* qh = (f16*)(ws + 0);                  // [16384][512] fp16 (dead after scores)
    f16* kh = (f16*)(ws + 16777216);           // [16384][512] fp16 (dead after scores)
    f16* P8 = (f16*)(ws + 33554432);           // [8][2048][2048] fp16 scores -> probs
    f16* Wt = (f16*)(ws + 33554432);           // [3][512][512] fp16 (aliases P8; dead after proj)
    f16* vt = (f16*)(ws + 0);                  // [8][512][2048] fp16 (aliases qh; written after scores)
    // d_out doubles as scratch until the final PV overwrites it:
    f16* xh = (f16*)d_out;                     // [16384][512] fp16
    f16* vv = (f16*)((char*)d_out + 16777216); // [16384][512] fp16

    k_cvt_x<<<8192, 256, 0, stream>>>(x, xh);
    k_cvt_w<<<3072, 256, 0, stream>>>(Wq, Wk, Wv, Wt);

    // QKV projections, one z=3 launch: M=16384, N=512, K=512 each
    k_gemm<true, true><<<dim3(4, 128, 3), 256, 0, stream>>>(
        xh, Wt, qh, vv, bq, bk, bv, 16384, 512, 512,
        0, (long)512 * 512, (long)16384 * 512);

    // scores: S[b] = q[b] k[b]^T, one z=8 launch, fp16 out
    k_gemm<true, false><<<dim3(16, 16, 8), 256, 0, stream>>>(
        qh, kh, P8, nullptr, nullptr, nullptr, nullptr, 2048, 2048, 512,
        (long)2048 * 512, (long)2048 * 512, (long)2048 * 2048);

    // transpose v (qh region is dead now; vt aliases it)
    k_transpose_v<<<dim3(16, 64, 8), 256, 0, stream>>>(vv, vt);

    // softmax in place on all 16384 rows
    k_softmax<<<16384, 256, 0, stream>>>(P8);

    // out[b] = P[b] v[b], one z=8 launch, fp32 out
    k_gemm<false, false><<<dim3(4, 16, 8), 256, 0, stream>>>(
        P8, vt, out, nullptr, nullptr, nullptr, nullptr, 2048, 512, 2048,
        (long)2048 * 2048, (long)512 * 2048, (long)2048 * 512);
}

// Round 3
// 198.642 us; speedup vs baseline: 1.9297x; 1.0708x over previous
//
#include <hip/hip_runtime.h>
#include <hip/hip_fp16.h>

// WordAttention on MI355X: fp16 MFMA pipeline, fully batched launches.
//   q,k,v = x@W + b (fp16);  S = q k^T (fp16, z=8);  P = softmax(S) in-place;  out = P v (fp32, z=8)
// GEMM K-loop: T3-minimum double-buffered prefetch (stage(next) -> compute(cur) -> 1 barrier).

typedef _Float16 f16;
typedef __attribute__((ext_vector_type(8))) _Float16 f16x8;
typedef __attribute__((ext_vector_type(4))) _Float16 f16x4;
typedef __attribute__((ext_vector_type(4))) float f32x4;

#define GADDR(p) ((const __attribute__((address_space(1))) void*)(p))
#define LADDR(p) ((__attribute__((address_space(3))) void*)(p))

// ---------------- convert x: fp32 -> fp16, 4 elems/thread ----------------
__global__ __launch_bounds__(256) void k_cvt_x(const float* __restrict__ in,
                                               f16* __restrict__ out) {
    long i = (long)blockIdx.x * 256 + threadIdx.x;
    float4 v = ((const float4*)in)[i];
    f16x4 h = { (f16)v.x, (f16)v.y, (f16)v.z, (f16)v.w };
    ((f16x4*)out)[i] = h;
}

// ------------- convert+transpose weights: Wt[w][n][k] = W[w][k][n] -------------
__global__ __launch_bounds__(256) void k_cvt_w(const float* __restrict__ Wq,
                                               const float* __restrict__ Wk,
                                               const float* __restrict__ Wv,
                                               f16* __restrict__ Wt) {
    int id = blockIdx.x * 256 + threadIdx.x;
    int w = id >> 18, rem = id & 262143;
    int kk = rem >> 9, n = rem & 511;
    const float* W = (w == 0) ? Wq : (w == 1) ? Wk : Wv;
    Wt[((long)w << 18) + ((long)n << 9) + kk] = (f16)W[((long)kk << 9) + n];
}

// ------------- per-batch transpose: Vt[b][d][s] = V[b*2048+s][d] -------------
__global__ __launch_bounds__(256) void k_transpose_v(const f16* __restrict__ V,
                                                     f16* __restrict__ Vt) {
    __shared__ f16 t[32][33];
    int b = blockIdx.z, s0 = blockIdx.y * 32, d0 = blockIdx.x * 32;
    int x = threadIdx.x & 31, y = threadIdx.x >> 5;
#pragma unroll
    for (int i = 0; i < 4; ++i)
        t[y + i * 8][x] = V[((long)(b * 2048 + s0 + y + i * 8) << 9) + d0 + x];
    __syncthreads();
#pragma unroll
    for (int i = 0; i < 4; ++i)
        Vt[((long)(b * 512 + d0 + y + i * 8) << 11) + s0 + x] = t[x][y + i * 8];
}

// ---------------- GEMM: C = A[M][K] * Bt[N][K]^T, 128x128 tile, BK=32 ----------------
// 4 waves each computing 64x64 (4x4 frags of 16x16x32 f16 MFMA).
// Double-buffered LDS; next tile's global_load_lds issued BEFORE computing current tile,
// so the implicit vmcnt(0) drain at the single per-iter barrier lands after compute.
template <bool OUT_F16, bool QKV>
__global__ __launch_bounds__(256) void k_gemm(const f16* __restrict__ A,
                                              const f16* __restrict__ Bt,
                                              void* __restrict__ Cv,
                                              void* __restrict__ CvAlt,
                                              const float* __restrict__ b0,
                                              const float* __restrict__ b1,
                                              const float* __restrict__ b2,
                                              int M, int N, int K,
                                              long sA, long sB, long sC) {
    const int bz = blockIdx.z;
    A  += bz * sA;
    Bt += bz * sB;
    __shared__ f16 As[2][128][32];
    __shared__ f16 Bs[2][128][32];
    const int tid = threadIdx.x;
    const int wave = tid >> 6, lane = tid & 63;
    const int l15 = lane & 15, l4 = lane >> 4;
    const int wm = (wave >> 1) * 64, wn = (wave & 1) * 64;
    const long rowA0 = (long)blockIdx.y * 128;
    const long rowB0 = (long)blockIdx.x * 128;

    const int trow = tid >> 2;           // 0..63
    const int tkc  = (tid & 3) * 8;      // k elem offset
    // per-wave LDS staging bases (wave-uniform base + lane*16, per HW contract)
    const int ldsOff = wave * 1024;

    // pre-bias global row pointers (k0 added per call)
    const f16* gA0 = A  + (rowA0 + trow)      * (long)K + tkc;
    const f16* gA1 = A  + (rowA0 + trow + 64) * (long)K + tkc;
    const f16* gB0 = Bt + (rowB0 + trow)      * (long)K + tkc;
    const f16* gB1 = Bt + (rowB0 + trow + 64) * (long)K + tkc;

    f32x4 acc[4][4] = {};

    auto stage = [&](int buf, int k0) {
        char* ab = (char*)&As[buf][0][0];
        char* bb = (char*)&Bs[buf][0][0];
        __builtin_amdgcn_global_load_lds(GADDR(gA0 + k0), LADDR(ab + ldsOff),        16, 0, 0);
        __builtin_amdgcn_global_load_lds(GADDR(gA1 + k0), LADDR(ab + 4096 + ldsOff), 16, 0, 0);
        __builtin_amdgcn_global_load_lds(GADDR(gB0 + k0), LADDR(bb + ldsOff),        16, 0, 0);
        __builtin_amdgcn_global_load_lds(GADDR(gB1 + k0), LADDR(bb + 4096 + ldsOff), 16, 0, 0);
    };

    const int nt = K >> 5;
    stage(0, 0);
    __syncthreads();                      // drains vmcnt -> buf0 ready
    int cur = 0;
    for (int t = 0; t < nt; ++t) {
        if (t + 1 < nt) stage(cur ^ 1, (t + 1) << 5);   // prefetch next tile

        f16x8 af[4], bf[4];
#pragma unroll
        for (int i = 0; i < 4; ++i)
            af[i] = *(const f16x8*)&As[cur][wm + i * 16 + l15][l4 * 8];
#pragma unroll
        for (int i = 0; i < 4; ++i)
            bf[i] = *(const f16x8*)&Bs[cur][wn + i * 16 + l15][l4 * 8];
#pragma unroll
        for (int i = 0; i < 4; ++i)
#pragma unroll
            for (int j = 0; j < 4; ++j)
                acc[i][j] = __builtin_amdgcn_mfma_f32_16x16x32_f16(af[i], bf[j], acc[i][j], 0, 0, 0);

        __syncthreads();                  // drains staging vmcnt + WAR for next stage
        cur ^= 1;
    }

    // epilogue: C/D layout col = lane&15, row = (lane>>4)*4 + reg  [m89-verified]
    const float* bias = nullptr;
    if constexpr (QKV) bias = (bz == 0) ? b0 : (bz == 1) ? b1 : b2;

    if constexpr (OUT_F16) {
        f16* C;
        if constexpr (QKV) C = (bz < 2) ? (f16*)Cv + bz * sC : (f16*)CvAlt;
        else               C = (f16*)Cv + bz * sC;
#pragma unroll
        for (int i = 0; i < 4; ++i)
#pragma unroll
            for (int j = 0; j < 4; ++j) {
                long gr = rowA0 + wm + i * 16 + l4 * 4;
                int  gc = (int)rowB0 + wn + j * 16 + l15;
                float bv_ = QKV ? bias[gc] : 0.f;
#pragma unroll
                for (int r = 0; r < 4; ++r)
                    C[(gr + r) * (long)N + gc] = (f16)(acc[i][j][r] + bv_);
            }
    } else {
        float* C = (float*)Cv + bz * sC;
#pragma unroll
        for (int i = 0; i < 4; ++i)
#pragma unroll
            for (int j = 0; j < 4; ++j) {
                long gr = rowA0 + wm + i * 16 + l4 * 4;
                int  gc = (int)rowB0 + wn + j * 16 + l15;
#pragma unroll
                for (int r = 0; r < 4; ++r)
                    C[(gr + r) * (long)N + gc] = acc[i][j][r];
            }
    }
}

// ---------------- row softmax in place: fp16 [2048 cols] ----------------
__global__ __launch_bounds__(256) void k_softmax(f16* __restrict__ P) {
    const long row = blockIdx.x;
    f16* p = P + row * 2048;
    const int tid = threadIdx.x, lane = tid & 63, wave = tid >> 6;

    f16x8 v = ((const f16x8*)p)[tid];
    float f[8];
#pragma unroll
    for (int j = 0; j < 8; ++j) f[j] = (float)v[j];
    float m = fmaxf(fmaxf(fmaxf(f[0], f[1]), fmaxf(f[2], f[3])),
                    fmaxf(fmaxf(f[4], f[5]), fmaxf(f[6], f[7])));
#pragma unroll
    for (int off = 32; off; off >>= 1) m = fmaxf(m, __shfl_xor(m, off));

    __shared__ float red[4];
    __shared__ float bc[2];
    if (lane == 0) red[wave] = m;
    __syncthreads();
    if (tid == 0) bc[0] = fmaxf(fmaxf(red[0], red[1]), fmaxf(red[2], red[3]));
    __syncthreads();
    m = bc[0];

    float e[8], sum = 0.f;
#pragma unroll
    for (int j = 0; j < 8; ++j) { e[j] = __expf(f[j] - m); sum += e[j]; }
#pragma unroll
    for (int off = 32; off; off >>= 1) sum += __shfl_xor(sum, off);
    if (lane == 0) red[wave] = sum;
    __syncthreads();
    if (tid == 0) bc[1] = (red[0] + red[1]) + (red[2] + red[3]);
    __syncthreads();
    float inv = 1.f / bc[1];

    f16x8 o;
#pragma unroll
    for (int j = 0; j < 8; ++j) o[j] = (f16)(e[j] * inv);
    ((f16x8*)p)[tid] = o;
}

extern "C" void kernel_launch(void* const* d_in, const int* in_sizes, int n_in,
                              void* d_out, int out_size, void* d_ws, size_t ws_size,
                              hipStream_t stream) {
    const float* x  = (const float*)d_in[0];
    const float* Wq = (const float*)d_in[1];
    const float* bq = (const float*)d_in[2];
    const float* Wk = (const float*)d_in[3];
    const float* bk = (const float*)d_in[4];
    const float* Wv = (const float*)d_in[5];
    const float* bv = (const float*)d_in[6];
    float* out = (float*)d_out;

    // ---- workspace layout (96 MiB peak, phase-aliased) ----
    char* ws = (char*)d_ws;
    f16* qh = (f16*)(ws + 0);                  // [16384][512] fp16 (dead after scores)
    f16* kh = (f16*)(ws + 16777216);           // [16384][512] fp16 (dead after scores)
    f16* P8 = (f16*)(ws + 33554432);           // [8][2048][2048] fp16 scores -> probs
    f16* Wt = (f16*)(ws + 33554432);           // [3][512][512] fp16 (aliases P8; dead after proj)
    f16* vt = (f16*)(ws + 0);                  // [8][512][2048] fp16 (aliases qh; written after scores)
    // d_out doubles as scratch until the final PV overwrites it:
    f16* xh = (f16*)d_out;                     // [16384][512] fp16
    f16* vv = (f16*)((char*)d_out + 16777216); // [16384][512] fp16

    k_cvt_x<<<8192, 256, 0, stream>>>(x, xh);
    k_cvt_w<<<3072, 256, 0, stream>>>(Wq, Wk, Wv, Wt);

    // QKV projections, one z=3 launch: M=16384, N=512, K=512 each
    k_gemm<true, true><<<dim3(4, 128, 3), 256, 0, stream>>>(
        xh, Wt, qh, vv, bq, bk, bv, 16384, 512, 512,
        0, (long)512 * 512, (long)16384 * 512);

    // scores: S[b] = q[b] k[b]^T, one z=8 launch, fp16 out
    k_gemm<true, false><<<dim3(16, 16, 8), 256, 0, stream>>>(
        qh, kh, P8, nullptr, nullptr, nullptr, nullptr, 2048, 2048, 512,
        (long)2048 * 512, (long)2048 * 512, (long)2048 * 2048);

    // transpose v (qh region is dead now; vt aliases it)
    k_transpose_v<<<dim3(16, 64, 8), 256, 0, stream>>>(vv, vt);

    // softmax in place on all 16384 rows
    k_softmax<<<16384, 256, 0, stream>>>(P8);

    // out[b] = P[b] v[b], one z=8 launch, fp32 out
    k_gemm<false, false><<<dim3(4, 16, 8), 256, 0, stream>>>(
        P8, vt, out, nullptr, nullptr, nullptr, nullptr, 2048, 512, 2048,
        (long)2048 * 2048, (long)512 * 2048, (long)2048 * 512);
}